// Round 24
// baseline (162.074 us; speedup 1.0000x reference)
//
#include <hip/hip_runtime.h>

#define H 128

typedef __attribute__((ext_vector_type(4))) float f32x4;
typedef __attribute__((ext_vector_type(8))) _Float16 half8;

struct NetParams { const float *Win, *bi, *Wh, *bh, *Wout, *bo; };

// fast tanh: graceful +-1 at overflow, ~1e-6 rel err
__device__ inline float fast_tanhf(float x) {
  float a = fabsf(x);
  float e = __expf(2.0f * a);
  float t = 1.0f - 2.0f * __builtin_amdgcn_rcpf(e + 1.0f);
  return copysignf(t, x);
}

// ---------------- tanh jet composition (compressed jets) ----------------
// JET=4: [u, zx, zy, Lz]            (Laplacian propagates closed-form)
// JET=8: [u, zx, zy, zxx, zxy, zyy, Lx, Ly]
template<int JET>
__device__ inline void tanh_jet(const float* z, float* o) {
  float t  = fast_tanhf(z[0]);
  o[0] = t;
  if constexpr (JET >= 4) {
    float t1 = 1.0f - t * t;
    float t2 = -2.0f * t * t1;
    float zx = z[1], zy = z[2];
    float S = zx * zx + zy * zy;
    o[1] = t1 * zx;
    o[2] = t1 * zy;
    if constexpr (JET == 4) {
      o[3] = t2 * S + t1 * z[3];                    // Lap(t o z)
    } else { // JET == 8
      float t3 = t1 * (6.0f * t * t - 2.0f);
      float zxx = z[3], zxy = z[4], zyy = z[5], Lx = z[6], Ly = z[7];
      float L = zxx + zyy;
      o[3] = t2 * zx * zx + t1 * zxx;
      o[4] = t2 * zx * zy + t1 * zxy;
      o[5] = t2 * zy * zy + t1 * zyy;
      float Sx = 2.0f * (zx * zxx + zy * zxy);
      float Sy = 2.0f * (zx * zxy + zy * zyy);
      o[6] = t3 * zx * S + t2 * (Sx + zx * L) + t1 * Lx;
      o[7] = t3 * zy * S + t2 * (Sy + zy * L) + t1 * Ly;
    }
  }
}

// X LDS layout [64 rows n][128 k=j] f16, XOR-swizzled at 8-elem (16B) blocks.
__device__ inline int xpos(int n, int k) {
  return n * H + (((k >> 3) ^ (n & 7)) << 3) + (k & 7);
}

// ---------------- MFMA network jet evaluation (swapped operands, f16) ------
template<int JET, int JETP, int NPTS>
__device__ void eval_mfma(const float* xs, const float* ys, int base,
                          const NetParams& P, const _Float16* wt,
                          _Float16* Xf, float* U) {
  const int t = threadIdx.x;
  const int lane = t & 63, wv = t >> 6;

  // ---- input layer: 2 -> H
  {
    int j = t & (H - 1);
    float w0 = P.Win[j], w1 = P.Win[H + j], b = P.bi[j];
#pragma unroll
    for (int i = 0; i < NPTS / 2; i++) {
      int p = (t + i * 256) >> 7;
      float xp = xs[base + p], yp = ys[base + p];
      float z[JET];
#pragma unroll
      for (int q = 0; q < JET; q++) z[q] = 0.0f;
      z[0] = xp * w0 + yp * w1 + b;
      if constexpr (JET >= 4) { z[1] = w0; z[2] = w1; }
      float o[JET];
      tanh_jet<JET>(z, o);
#pragma unroll
      for (int q = 0; q < JET; q++)
        Xf[xpos(p * JETP + q, j)] = (_Float16)o[q];
    }
  }
  __syncthreads();

  const int jl = lane & 15, kg = lane >> 4;
  const int j0 = wv * 32 + jl;        // jt=0 column of this lane
  const int j1 = j0 + 16;             // jt=1 column
  float bh00 = P.bh[j0],         bh01 = P.bh[j1];
  float bh10 = P.bh[H + j0],     bh11 = P.bh[H + j1];
  float bh20 = P.bh[2 * H + j0], bh21 = P.bh[2 * H + j1];

  // ---- 3 hidden layers
  for (int l = 0; l < 3; l++) {
    const _Float16* Wl = wt + l * H * H;

    f32x4 acc[4][2];
#pragma unroll
    for (int nt = 0; nt < 4; nt++) {
      f32x4 z4 = {0.f, 0.f, 0.f, 0.f};
      acc[nt][0] = z4; acc[nt][1] = z4;
    }

    // MFMA cluster (32 MFMAs), ks-outer: W residency 8 VGPR
#pragma unroll
    for (int ks = 0; ks < 4; ks++) {
      const int koff = ks * 32 + kg * 8;
      half8 B0 = *(const half8*)(Wl + j0 * H + koff);
      half8 B1 = *(const half8*)(Wl + j1 * H + koff);
      const int kb = ks * 4 + kg;
#pragma unroll
      for (int nt = 0; nt < 4; nt++) {
        const int n = nt * 16 + jl;
        half8 A = *(const half8*)(Xf + n * H + ((kb ^ (n & 7)) << 3));
        acc[nt][0] = __builtin_amdgcn_mfma_f32_16x16x32_f16(A, B0, acc[nt][0], 0, 0, 0);
        acc[nt][1] = __builtin_amdgcn_mfma_f32_16x16x32_f16(A, B1, acc[nt][1], 0, 0, 0);
      }
    }
    __syncthreads();   // all waves done READING X(l); X(l) now dead

    float bhv0 = (l == 0) ? bh00 : ((l == 1) ? bh10 : bh20);
    float bhv1 = (l == 0) ? bh01 : ((l == 1) ? bh11 : bh21);

    // jet pass: directly on acc registers, write X(l+1)
#pragma unroll
    for (int nt = 0; nt < 4; nt++) {
#pragma unroll
      for (int jt = 0; jt < 2; jt++) {
        const int j = jt ? j1 : j0;
        const float bhv = jt ? bhv1 : bhv0;
        f32x4 a = acc[nt][jt];
        if constexpr (JETP == 4) {
          float z[4] = {a[0] + bhv, a[1], a[2], a[3]};
          float o[4];
          tanh_jet<4>(z, o);
#pragma unroll
          for (int q = 0; q < 4; q++)
            Xf[xpos(nt * 16 + kg * 4 + q, j)] = (_Float16)o[q];
        } else if constexpr (JETP == 1) {
#pragma unroll
          for (int q = 0; q < 4; q++) {
            float o0 = fast_tanhf(a[q] + bhv);
            Xf[xpos(nt * 16 + kg * 4 + q, j)] = (_Float16)o0;
          }
        } else { // JETP == 8: half-exchange with lane^16 (same column j)
          float p0 = __shfl_xor(a[0], 16);
          float p1 = __shfl_xor(a[1], 16);
          float p2 = __shfl_xor(a[2], 16);
          float p3 = __shfl_xor(a[3], 16);
          const bool hi_half = (kg & 1);
          float z[8];
          z[0] = (hi_half ? p0 : a[0]) + bhv;
          z[1] = hi_half ? p1 : a[1];
          z[2] = hi_half ? p2 : a[2];
          z[3] = hi_half ? p3 : a[3];
          z[4] = hi_half ? a[0] : p0;
          z[5] = hi_half ? a[1] : p1;
          z[6] = hi_half ? a[2] : p2;
          z[7] = hi_half ? a[3] : p3;
          float o[8];
          tanh_jet<8>(z, o);
          float w0 = hi_half ? o[4] : o[0];
          float w1 = hi_half ? o[5] : o[1];
          float w2 = hi_half ? o[6] : o[2];
          float w3 = hi_half ? o[7] : o[3];
          float w[4] = {w0, w1, w2, w3};
#pragma unroll
          for (int q = 0; q < 4; q++)
            Xf[xpos(nt * 16 + kg * 4 + q, j)] = (_Float16)w[q];
        }
      }
    }
    __syncthreads();   // X(l+1) complete block-wide
  }

  // ---- output layer: u[n] = sum_k Wout[k]*x + bo
  float s;
  {
    int n = t >> 2, qt = t & 3;
    s = 0.f;
#pragma unroll
    for (int b = 0; b < 4; b++) {
      int kb = qt * 4 + b;
      half8 h8 = *(const half8*)(Xf + n * H + ((kb ^ (n & 7)) << 3));
#pragma unroll
      for (int i = 0; i < 8; i++) {
        float w = P.Wout[kb * 8 + i];
        s += w * (float)h8[i];
      }
    }
  }
  __syncthreads();               // all X reads done; Xf is now f32 scratch
  float* Sc = (float*)Xf;
  Sc[t] = s;
  __syncthreads();
  if (t < 64)
    U[t] = Sc[t * 4] + Sc[t * 4 + 1] + Sc[t * 4 + 2] + Sc[t * 4 + 3] + P.bo[0];
  __syncthreads();
}

// ---------------- ws layout ----------------
#define WS_RES1 0
#define WS_RES2 4096
#define WS_BND1 8192
#define WS_BND2 8704
#define WS_SUMS 8448      // 13 partial sums (gap between bnd regions)
#define WS_INTF 9216
#define WT_BYTE_OFF 73728
#define WT_COUNT (2 * 3 * H * H)

#define NRES_BLK 2048    // 32768/16 (exact)
#define NBND_BLK 64      // 4096/64  (exact)
#define NINT_BLK 512     // 4096/8   (exact)

// ---------------- prep: transpose + f16-round both nets' Wh ----------------
__global__ void __launch_bounds__(256) prep_kernel(
    const float* Wh1, const float* Wh2, _Float16* wt) {
  int o = blockIdx.x * 256 + threadIdx.x;
  if (o >= WT_COUNT) return;
  int net = o / (3 * H * H);
  int r = o - net * 3 * H * H;
  int l = r >> 14, j = (r >> 7) & (H - 1), k = r & (H - 1);
  const float* W = (net ? Wh2 : Wh1);
  wt[o] = (_Float16)W[(l * H + k) * H + j];   // RNE cast
}

// ---------------- fused eval kernel ----------------
// (256,8): force the 64-VGPR hardware bucket (wave capacity steps at
// 64/128/256) -> 8 waves/SIMD. ~20 regs of spill tax vs doubled latency
// cover; R20 measured this tradeoff favorable on the heavier structure.
__global__ void __launch_bounds__(256, 8) fused_kernel(
    const float* xb1, const float* yb1, const float* ub1,
    const float* xb2, const float* yb2, const float* ub2,
    const float* xf1, const float* yf1, const float* ff1,
    const float* xf2, const float* yf2, const float* ff2,
    const float* xi, const float* yi, const float* fi,
    NetParams P1, NetParams P2, const _Float16* wt, float* ws) {
  __shared__ __align__(16) _Float16 Xf[64 * H];
  const int t = threadIdx.x;
  const int b = blockIdx.x;
  float* Sc = (float*)Xf;
  float* U = Sc + 256;

  if (b < NINT_BLK) {
    // ---------- interface: 8 points, JETP=8 (64/64 rows) ----------
    const int base = b * 8;
    eval_mfma<8, 8, 8>(xi, yi, base, P1, wt, Xf, U);
    float u1v = 0.f;
    if (t < 64) u1v = U[t];
    __syncthreads();
    eval_mfma<8, 8, 8>(xi, yi, base, P2, wt + 3 * H * H, Xf, U);
    if (t < 64) Sc[320 + t] = u1v;
    __syncthreads();
    if (t < 8) {
      // per point: [u, ux, uy, uxx, uxy, uyy, Lx, Ly]
      const float* a = Sc + 320 + t * 8;   // U1
      const float* bb = U + t * 8;         // U2
      float fsrc = fi[base + t];
      float f1 = a[3] + a[5] - fsrc;
      float f2 = bb[3] + bb[5] - fsrc;
      float du = a[0] - bb[0];
      float fd = f1 - f2;
      float dfl = a[2] - bb[2];
      float dyy = a[5] - bb[5];
      float dx  = a[1] - bb[1];
      float dxx = a[3] - bb[3];
      float* T = Sc + 384 + t * 9;
      T[0] = du * du;
      T[1] = f1 * f1;
      T[2] = f2 * f2;
      T[3] = fd * fd;
      T[4] = dfl * dfl;
      T[5] = a[6] * a[6] + a[7] * a[7] + bb[6] * bb[6] + bb[7] * bb[7];
      T[6] = dyy * dyy;
      T[7] = dx * dx;
      T[8] = dxx * dxx;
    }
    __syncthreads();
    if (t < 9) {
      float s = 0.f;
#pragma unroll
      for (int i = 0; i < 8; i++) s += Sc[384 + i * 9 + t];
      ws[WS_INTF + t * 1024 + b] = s;
    }
  } else if (b < NINT_BLK + 2 * NRES_BLK) {
    // ---------- residual: 16 points, JETP=4 (64/64 rows) ----------
    const int r = b - NINT_BLK;
    const int net = (r >= NRES_BLK) ? 1 : 0;
    const int rb = net ? (r - NRES_BLK) : r;
    const float* xs = net ? xf2 : xf1;
    const float* ys = net ? yf2 : yf1;
    const float* fs = net ? ff2 : ff1;
    NetParams P = net ? P2 : P1;
    const _Float16* wtn = wt + net * 3 * H * H;
    const int base = rb * 16;
    eval_mfma<4, 4, 16>(xs, ys, base, P, wtn, Xf, U);
    if (t < 16) {
      float f = U[t * 4 + 3] - fs[base + t];   // lap - ff
      Sc[320 + t] = f * f;
    }
    __syncthreads();
    if (t == 0) {
      float s = 0.f;
#pragma unroll
      for (int i = 0; i < 16; i++) s += Sc[320 + i];
      ws[(net ? WS_RES2 : WS_RES1) + rb] = s;
    }
  } else {
    // ---------- boundary: 64 points, JETP=1 ----------
    const int r = b - NINT_BLK - 2 * NRES_BLK;
    const int net = (r >= NBND_BLK) ? 1 : 0;
    const int rb = net ? (r - NBND_BLK) : r;
    const float* xs = net ? xb2 : xb1;
    const float* ys = net ? yb2 : yb1;
    const float* us = net ? ub2 : ub1;
    NetParams P = net ? P2 : P1;
    const _Float16* wtn = wt + net * 3 * H * H;
    const int base = rb * 64;
    eval_mfma<1, 1, 64>(xs, ys, base, P, wtn, Xf, U);
    if (t < 64) {
      float d = us[base + t] - U[t];
      Sc[320 + t] = d * d;
    }
    __syncthreads();
    if (t == 0) {
      float s = 0.f;
#pragma unroll
      for (int i = 0; i < 64; i++) s += Sc[320 + i];
      ws[(net ? WS_BND2 : WS_BND1) + rb] = s;
    }
  }
}

// ---------------- combine stage A: 13 parallel region reductions ----------
__global__ void __launch_bounds__(256) combine_a_kernel(
    const float* ws, float* ws_sums) {
  __shared__ float red[256];
  const int t = threadIdx.x;
  const int r = blockIdx.x;
  const int off[13] = {WS_RES1, WS_RES2, WS_BND1, WS_BND2,
                       WS_INTF + 0 * 1024, WS_INTF + 1 * 1024, WS_INTF + 2 * 1024,
                       WS_INTF + 3 * 1024, WS_INTF + 4 * 1024, WS_INTF + 5 * 1024,
                       WS_INTF + 6 * 1024, WS_INTF + 7 * 1024, WS_INTF + 8 * 1024};
  const int len[13] = {NRES_BLK, NRES_BLK, NBND_BLK, NBND_BLK,
                       NINT_BLK, NINT_BLK, NINT_BLK, NINT_BLK, NINT_BLK,
                       NINT_BLK, NINT_BLK, NINT_BLK, NINT_BLK};
  float s = 0.f;
  for (int i = t; i < len[r]; i += 256) s += ws[off[r] + i];
  red[t] = s;
  __syncthreads();
  for (int w = 128; w > 0; w >>= 1) {
    if (t < w) red[t] += red[t + w];
    __syncthreads();
  }
  if (t == 0) ws_sums[r] = red[0];
}

// ---------------- combine stage B: final weighted sum ----------------
__global__ void combine_b_kernel(const float* ws_sums, const float* iw,
                                 float* out) {
  if (threadIdx.x != 0) return;
  float sums[13];
#pragma unroll
  for (int r = 0; r < 13; r++) sums[r] = ws_sums[r];
  const float Nf = 32768.0f, Nb = 4096.0f, Ni = 4096.0f;
  float mse_f  = (sums[0] + sums[1]) / Nf;
  float mse_ub = (sums[2] + sums[3]) / Nb;
  float su = sums[4];
  float mse_i_u    = su / Ni;
  float mse_i_uavg = su / (2.0f * Ni);
  float mse_i_res  = (sums[5] + sums[6]) / Ni;
  float mse_cont   = sums[7] / Ni;
  float mse_flux   = sums[8] / Ni;
  float mse_gres   = sums[9] / Ni;
  float mse_uyy    = sums[10] / Ni;
  float mse_ux     = sums[11] / Ni;
  float mse_uxx    = sums[12] / Ni;
  float il = iw[0] * mse_i_u + iw[1] * mse_i_uavg + iw[2] * mse_i_res
           + iw[3] * mse_cont + iw[4] * mse_flux + iw[6] * mse_gres
           + iw[5] * mse_uyy + iw[7] * mse_ux + iw[8] * mse_uxx;
  out[0] = 20.0f * mse_ub + mse_f + 5.0f * il;
}

extern "C" void kernel_launch(void* const* d_in, const int* in_sizes, int n_in,
                              void* d_out, int out_size, void* d_ws, size_t ws_size,
                              hipStream_t stream) {
  const float* xb1 = (const float*)d_in[0];
  const float* yb1 = (const float*)d_in[1];
  const float* ub1 = (const float*)d_in[2];
  const float* xb2 = (const float*)d_in[3];
  const float* yb2 = (const float*)d_in[4];
  const float* ub2 = (const float*)d_in[5];
  const float* xf1 = (const float*)d_in[6];
  const float* yf1 = (const float*)d_in[7];
  const float* ff1 = (const float*)d_in[8];
  const float* xf2 = (const float*)d_in[9];
  const float* yf2 = (const float*)d_in[10];
  const float* ff2 = (const float*)d_in[11];
  const float* xi1 = (const float*)d_in[12];
  const float* yi1 = (const float*)d_in[13];
  const float* fi1 = (const float*)d_in[14];
  const float* iw  = (const float*)d_in[15];
  NetParams P1 = {(const float*)d_in[16], (const float*)d_in[17],
                  (const float*)d_in[18], (const float*)d_in[19],
                  (const float*)d_in[20], (const float*)d_in[21]};
  NetParams P2 = {(const float*)d_in[22], (const float*)d_in[23],
                  (const float*)d_in[24], (const float*)d_in[25],
                  (const float*)d_in[26], (const float*)d_in[27]};
  float* ws = (float*)d_ws;
  float* out = (float*)d_out;
  _Float16* wt = (_Float16*)((char*)d_ws + WT_BYTE_OFF);

  hipLaunchKernelGGL(prep_kernel, dim3((WT_COUNT + 255) / 256), dim3(256), 0, stream,
                     P1.Wh, P2.Wh, wt);
  const int NBLK = NINT_BLK + 2 * NRES_BLK + 2 * NBND_BLK;
  hipLaunchKernelGGL(fused_kernel, dim3(NBLK), dim3(256), 0, stream,
                     xb1, yb1, ub1, xb2, yb2, ub2,
                     xf1, yf1, ff1, xf2, yf2, ff2,
                     xi1, yi1, fi1, P1, P2, wt, ws);
  hipLaunchKernelGGL(combine_a_kernel, dim3(13), dim3(256), 0, stream,
                     ws, ws + WS_SUMS);
  hipLaunchKernelGGL(combine_b_kernel, dim3(1), dim3(64), 0, stream,
                     ws + WS_SUMS, iw, out);
}

// Round 25
// 112.098 us; speedup vs baseline: 1.4458x; 1.4458x over previous
//
#include <hip/hip_runtime.h>

#define H 128

typedef __attribute__((ext_vector_type(4))) float f32x4;
typedef __attribute__((ext_vector_type(8))) _Float16 half8;

struct NetParams { const float *Win, *bi, *Wh, *bh, *Wout, *bo; };

// fast tanh: graceful +-1 at overflow, ~1e-6 rel err
__device__ inline float fast_tanhf(float x) {
  float a = fabsf(x);
  float e = __expf(2.0f * a);
  float t = 1.0f - 2.0f * __builtin_amdgcn_rcpf(e + 1.0f);
  return copysignf(t, x);
}

// ---------------- tanh jet composition (compressed jets) ----------------
// JET=4: [u, zx, zy, Lz]            (Laplacian propagates closed-form)
// JET=8: [u, zx, zy, zxx, zxy, zyy, Lx, Ly]
template<int JET>
__device__ inline void tanh_jet(const float* z, float* o) {
  float t  = fast_tanhf(z[0]);
  o[0] = t;
  if constexpr (JET >= 4) {
    float t1 = 1.0f - t * t;
    float t2 = -2.0f * t * t1;
    float zx = z[1], zy = z[2];
    float S = zx * zx + zy * zy;
    o[1] = t1 * zx;
    o[2] = t1 * zy;
    if constexpr (JET == 4) {
      o[3] = t2 * S + t1 * z[3];                    // Lap(t o z)
    } else { // JET == 8
      float t3 = t1 * (6.0f * t * t - 2.0f);
      float zxx = z[3], zxy = z[4], zyy = z[5], Lx = z[6], Ly = z[7];
      float L = zxx + zyy;
      o[3] = t2 * zx * zx + t1 * zxx;
      o[4] = t2 * zx * zy + t1 * zxy;
      o[5] = t2 * zy * zy + t1 * zyy;
      float Sx = 2.0f * (zx * zxx + zy * zxy);
      float Sy = 2.0f * (zx * zxy + zy * zyy);
      o[6] = t3 * zx * S + t2 * (Sx + zx * L) + t1 * Lx;
      o[7] = t3 * zy * S + t2 * (Sy + zy * L) + t1 * Ly;
    }
  }
}

// X LDS layout [64 rows n][128 k=j] f16, XOR-swizzled at 8-elem (16B) blocks.
__device__ inline int xpos(int n, int k) {
  return n * H + (((k >> 3) ^ (n & 7)) << 3) + (k & 7);
}

// ---------------- MFMA network jet evaluation (swapped operands, f16) ------
// Block = 256 threads (4 waves). 64 GEMM rows n = NPTS x JETP exactly.
// mfma_f32_16x16x32_f16(A=X-frag, B=W-frag): D row = n = kg*4+reg (+nt*16),
// col = j = jl (+jt*16+wv*32). Jet composition directly on acc registers.
template<int JET, int JETP, int NPTS>
__device__ void eval_mfma(const float* xs, const float* ys, int base,
                          const NetParams& P, const _Float16* wt,
                          _Float16* Xf, float* U) {
  const int t = threadIdx.x;
  const int lane = t & 63, wv = t >> 6;

  // ---- input layer: 2 -> H
  {
    int j = t & (H - 1);
    float w0 = P.Win[j], w1 = P.Win[H + j], b = P.bi[j];
#pragma unroll
    for (int i = 0; i < NPTS / 2; i++) {
      int p = (t + i * 256) >> 7;
      float xp = xs[base + p], yp = ys[base + p];
      float z[JET];
#pragma unroll
      for (int q = 0; q < JET; q++) z[q] = 0.0f;
      z[0] = xp * w0 + yp * w1 + b;
      if constexpr (JET >= 4) { z[1] = w0; z[2] = w1; }
      float o[JET];
      tanh_jet<JET>(z, o);
#pragma unroll
      for (int q = 0; q < JET; q++)
        Xf[xpos(p * JETP + q, j)] = (_Float16)o[q];
    }
  }
  __syncthreads();

  const int jl = lane & 15, kg = lane >> 4;
  const int j0 = wv * 32 + jl;        // jt=0 column of this lane
  const int j1 = j0 + 16;             // jt=1 column
  float bh00 = P.bh[j0],         bh01 = P.bh[j1];
  float bh10 = P.bh[H + j0],     bh11 = P.bh[H + j1];
  float bh20 = P.bh[2 * H + j0], bh21 = P.bh[2 * H + j1];

  // ---- 3 hidden layers
  for (int l = 0; l < 3; l++) {
    const _Float16* Wl = wt + l * H * H;

    f32x4 acc[4][2];
#pragma unroll
    for (int nt = 0; nt < 4; nt++) {
      f32x4 z4 = {0.f, 0.f, 0.f, 0.f};
      acc[nt][0] = z4; acc[nt][1] = z4;
    }

    // MFMA cluster (32 MFMAs), ks-outer: W residency 8 VGPR
#pragma unroll
    for (int ks = 0; ks < 4; ks++) {
      const int koff = ks * 32 + kg * 8;
      half8 B0 = *(const half8*)(Wl + j0 * H + koff);
      half8 B1 = *(const half8*)(Wl + j1 * H + koff);
      const int kb = ks * 4 + kg;
#pragma unroll
      for (int nt = 0; nt < 4; nt++) {
        const int n = nt * 16 + jl;
        half8 A = *(const half8*)(Xf + n * H + ((kb ^ (n & 7)) << 3));
        acc[nt][0] = __builtin_amdgcn_mfma_f32_16x16x32_f16(A, B0, acc[nt][0], 0, 0, 0);
        acc[nt][1] = __builtin_amdgcn_mfma_f32_16x16x32_f16(A, B1, acc[nt][1], 0, 0, 0);
      }
    }
    __syncthreads();   // all waves done READING X(l); X(l) now dead

    float bhv0 = (l == 0) ? bh00 : ((l == 1) ? bh10 : bh20);
    float bhv1 = (l == 0) ? bh01 : ((l == 1) ? bh11 : bh21);

    // jet pass: directly on acc registers, write X(l+1)
#pragma unroll
    for (int nt = 0; nt < 4; nt++) {
#pragma unroll
      for (int jt = 0; jt < 2; jt++) {
        const int j = jt ? j1 : j0;
        const float bhv = jt ? bhv1 : bhv0;
        f32x4 a = acc[nt][jt];
        if constexpr (JETP == 4) {
          float z[4] = {a[0] + bhv, a[1], a[2], a[3]};
          float o[4];
          tanh_jet<4>(z, o);
#pragma unroll
          for (int q = 0; q < 4; q++)
            Xf[xpos(nt * 16 + kg * 4 + q, j)] = (_Float16)o[q];
        } else if constexpr (JETP == 1) {
#pragma unroll
          for (int q = 0; q < 4; q++) {
            float o0 = fast_tanhf(a[q] + bhv);
            Xf[xpos(nt * 16 + kg * 4 + q, j)] = (_Float16)o0;
          }
        } else { // JETP == 8: half-exchange with lane^16 (same column j)
          float p0 = __shfl_xor(a[0], 16);
          float p1 = __shfl_xor(a[1], 16);
          float p2 = __shfl_xor(a[2], 16);
          float p3 = __shfl_xor(a[3], 16);
          const bool hi_half = (kg & 1);
          float z[8];
          z[0] = (hi_half ? p0 : a[0]) + bhv;
          z[1] = hi_half ? p1 : a[1];
          z[2] = hi_half ? p2 : a[2];
          z[3] = hi_half ? p3 : a[3];
          z[4] = hi_half ? a[0] : p0;
          z[5] = hi_half ? a[1] : p1;
          z[6] = hi_half ? a[2] : p2;
          z[7] = hi_half ? a[3] : p3;
          float o[8];
          tanh_jet<8>(z, o);
          float w0 = hi_half ? o[4] : o[0];
          float w1 = hi_half ? o[5] : o[1];
          float w2 = hi_half ? o[6] : o[2];
          float w3 = hi_half ? o[7] : o[3];
          float w[4] = {w0, w1, w2, w3};
#pragma unroll
          for (int q = 0; q < 4; q++)
            Xf[xpos(nt * 16 + kg * 4 + q, j)] = (_Float16)w[q];
        }
      }
    }
    __syncthreads();   // X(l+1) complete block-wide
  }

  // ---- output layer: u[n] = sum_k Wout[k]*x + bo
  float s;
  {
    int n = t >> 2, qt = t & 3;
    s = 0.f;
#pragma unroll
    for (int b = 0; b < 4; b++) {
      int kb = qt * 4 + b;
      half8 h8 = *(const half8*)(Xf + n * H + ((kb ^ (n & 7)) << 3));
#pragma unroll
      for (int i = 0; i < 8; i++) {
        float w = P.Wout[kb * 8 + i];
        s += w * (float)h8[i];
      }
    }
  }
  __syncthreads();               // all X reads done; Xf is now f32 scratch
  float* Sc = (float*)Xf;
  Sc[t] = s;
  __syncthreads();
  if (t < 64)
    U[t] = Sc[t * 4] + Sc[t * 4 + 1] + Sc[t * 4 + 2] + Sc[t * 4 + 3] + P.bo[0];
  __syncthreads();
}

// ---------------- ws layout ----------------
#define WS_RES1 0
#define WS_RES2 4096
#define WS_BND1 8192
#define WS_BND2 8704
#define WS_SUMS 8448      // 13 partial sums (gap between bnd regions)
#define WS_INTF 9216
#define WT_BYTE_OFF 73728
#define WT_COUNT (2 * 3 * H * H)

#define NRES_BLK 2048    // 32768/16 (exact)
#define NBND_BLK 64      // 4096/64  (exact)
#define NINT_BLK 512     // 4096/8   (exact)

// ---------------- prep: transpose + f16-round both nets' Wh ----------------
__global__ void __launch_bounds__(256) prep_kernel(
    const float* Wh1, const float* Wh2, _Float16* wt) {
  int o = blockIdx.x * 256 + threadIdx.x;
  if (o >= WT_COUNT) return;
  int net = o / (3 * H * H);
  int r = o - net * 3 * H * H;
  int l = r >> 14, j = (r >> 7) & (H - 1), k = r & (H - 1);
  const float* W = (net ? Wh2 : Wh1);
  wt[o] = (_Float16)W[(l * H + k) * H + j];   // RNE cast
}

// ---------------- fused eval kernel ----------------
// (256,3): R23's best configuration — VGPR 84, zero spill, 113us fused.
// (R24's (256,8) forced VGPR->32 with 500MB spill traffic: -54% regression.)
__global__ void __launch_bounds__(256, 3) fused_kernel(
    const float* xb1, const float* yb1, const float* ub1,
    const float* xb2, const float* yb2, const float* ub2,
    const float* xf1, const float* yf1, const float* ff1,
    const float* xf2, const float* yf2, const float* ff2,
    const float* xi, const float* yi, const float* fi,
    NetParams P1, NetParams P2, const _Float16* wt, float* ws) {
  __shared__ __align__(16) _Float16 Xf[64 * H];
  const int t = threadIdx.x;
  const int b = blockIdx.x;
  float* Sc = (float*)Xf;
  float* U = Sc + 256;

  if (b < NINT_BLK) {
    // ---------- interface: 8 points, JETP=8 (64/64 rows) ----------
    const int base = b * 8;
    eval_mfma<8, 8, 8>(xi, yi, base, P1, wt, Xf, U);
    float u1v = 0.f;
    if (t < 64) u1v = U[t];
    __syncthreads();
    eval_mfma<8, 8, 8>(xi, yi, base, P2, wt + 3 * H * H, Xf, U);
    if (t < 64) Sc[320 + t] = u1v;
    __syncthreads();
    if (t < 8) {
      // per point: [u, ux, uy, uxx, uxy, uyy, Lx, Ly]
      const float* a = Sc + 320 + t * 8;   // U1
      const float* bb = U + t * 8;         // U2
      float fsrc = fi[base + t];
      float f1 = a[3] + a[5] - fsrc;
      float f2 = bb[3] + bb[5] - fsrc;
      float du = a[0] - bb[0];
      float fd = f1 - f2;
      float dfl = a[2] - bb[2];
      float dyy = a[5] - bb[5];
      float dx  = a[1] - bb[1];
      float dxx = a[3] - bb[3];
      float* T = Sc + 384 + t * 9;
      T[0] = du * du;
      T[1] = f1 * f1;
      T[2] = f2 * f2;
      T[3] = fd * fd;
      T[4] = dfl * dfl;
      T[5] = a[6] * a[6] + a[7] * a[7] + bb[6] * bb[6] + bb[7] * bb[7];
      T[6] = dyy * dyy;
      T[7] = dx * dx;
      T[8] = dxx * dxx;
    }
    __syncthreads();
    if (t < 9) {
      float s = 0.f;
#pragma unroll
      for (int i = 0; i < 8; i++) s += Sc[384 + i * 9 + t];
      ws[WS_INTF + t * 1024 + b] = s;
    }
  } else if (b < NINT_BLK + 2 * NRES_BLK) {
    // ---------- residual: 16 points, JETP=4 (64/64 rows) ----------
    const int r = b - NINT_BLK;
    const int net = (r >= NRES_BLK) ? 1 : 0;
    const int rb = net ? (r - NRES_BLK) : r;
    const float* xs = net ? xf2 : xf1;
    const float* ys = net ? yf2 : yf1;
    const float* fs = net ? ff2 : ff1;
    NetParams P = net ? P2 : P1;
    const _Float16* wtn = wt + net * 3 * H * H;
    const int base = rb * 16;
    eval_mfma<4, 4, 16>(xs, ys, base, P, wtn, Xf, U);
    if (t < 16) {
      float f = U[t * 4 + 3] - fs[base + t];   // lap - ff
      Sc[320 + t] = f * f;
    }
    __syncthreads();
    if (t == 0) {
      float s = 0.f;
#pragma unroll
      for (int i = 0; i < 16; i++) s += Sc[320 + i];
      ws[(net ? WS_RES2 : WS_RES1) + rb] = s;
    }
  } else {
    // ---------- boundary: 64 points, JETP=1 ----------
    const int r = b - NINT_BLK - 2 * NRES_BLK;
    const int net = (r >= NBND_BLK) ? 1 : 0;
    const int rb = net ? (r - NBND_BLK) : r;
    const float* xs = net ? xb2 : xb1;
    const float* ys = net ? yb2 : yb1;
    const float* us = net ? ub2 : ub1;
    NetParams P = net ? P2 : P1;
    const _Float16* wtn = wt + net * 3 * H * H;
    const int base = rb * 64;
    eval_mfma<1, 1, 64>(xs, ys, base, P, wtn, Xf, U);
    if (t < 64) {
      float d = us[base + t] - U[t];
      Sc[320 + t] = d * d;
    }
    __syncthreads();
    if (t == 0) {
      float s = 0.f;
#pragma unroll
      for (int i = 0; i < 64; i++) s += Sc[320 + i];
      ws[(net ? WS_BND2 : WS_BND1) + rb] = s;
    }
  }
}

// ---------------- combine stage A: 13 parallel region reductions ----------
__global__ void __launch_bounds__(256) combine_a_kernel(
    const float* ws, float* ws_sums) {
  __shared__ float red[256];
  const int t = threadIdx.x;
  const int r = blockIdx.x;
  const int off[13] = {WS_RES1, WS_RES2, WS_BND1, WS_BND2,
                       WS_INTF + 0 * 1024, WS_INTF + 1 * 1024, WS_INTF + 2 * 1024,
                       WS_INTF + 3 * 1024, WS_INTF + 4 * 1024, WS_INTF + 5 * 1024,
                       WS_INTF + 6 * 1024, WS_INTF + 7 * 1024, WS_INTF + 8 * 1024};
  const int len[13] = {NRES_BLK, NRES_BLK, NBND_BLK, NBND_BLK,
                       NINT_BLK, NINT_BLK, NINT_BLK, NINT_BLK, NINT_BLK,
                       NINT_BLK, NINT_BLK, NINT_BLK, NINT_BLK};
  float s = 0.f;
  for (int i = t; i < len[r]; i += 256) s += ws[off[r] + i];
  red[t] = s;
  __syncthreads();
  for (int w = 128; w > 0; w >>= 1) {
    if (t < w) red[t] += red[t + w];
    __syncthreads();
  }
  if (t == 0) ws_sums[r] = red[0];
}

// ---------------- combine stage B: final weighted sum ----------------
__global__ void combine_b_kernel(const float* ws_sums, const float* iw,
                                 float* out) {
  if (threadIdx.x != 0) return;
  float sums[13];
#pragma unroll
  for (int r = 0; r < 13; r++) sums[r] = ws_sums[r];
  const float Nf = 32768.0f, Nb = 4096.0f, Ni = 4096.0f;
  float mse_f  = (sums[0] + sums[1]) / Nf;
  float mse_ub = (sums[2] + sums[3]) / Nb;
  float su = sums[4];
  float mse_i_u    = su / Ni;
  float mse_i_uavg = su / (2.0f * Ni);
  float mse_i_res  = (sums[5] + sums[6]) / Ni;
  float mse_cont   = sums[7] / Ni;
  float mse_flux   = sums[8] / Ni;
  float mse_gres   = sums[9] / Ni;
  float mse_uyy    = sums[10] / Ni;
  float mse_ux     = sums[11] / Ni;
  float mse_uxx    = sums[12] / Ni;
  float il = iw[0] * mse_i_u + iw[1] * mse_i_uavg + iw[2] * mse_i_res
           + iw[3] * mse_cont + iw[4] * mse_flux + iw[6] * mse_gres
           + iw[5] * mse_uyy + iw[7] * mse_ux + iw[8] * mse_uxx;
  out[0] = 20.0f * mse_ub + mse_f + 5.0f * il;
}

extern "C" void kernel_launch(void* const* d_in, const int* in_sizes, int n_in,
                              void* d_out, int out_size, void* d_ws, size_t ws_size,
                              hipStream_t stream) {
  const float* xb1 = (const float*)d_in[0];
  const float* yb1 = (const float*)d_in[1];
  const float* ub1 = (const float*)d_in[2];
  const float* xb2 = (const float*)d_in[3];
  const float* yb2 = (const float*)d_in[4];
  const float* ub2 = (const float*)d_in[5];
  const float* xf1 = (const float*)d_in[6];
  const float* yf1 = (const float*)d_in[7];
  const float* ff1 = (const float*)d_in[8];
  const float* xf2 = (const float*)d_in[9];
  const float* yf2 = (const float*)d_in[10];
  const float* ff2 = (const float*)d_in[11];
  const float* xi1 = (const float*)d_in[12];
  const float* yi1 = (const float*)d_in[13];
  const float* fi1 = (const float*)d_in[14];
  const float* iw  = (const float*)d_in[15];
  NetParams P1 = {(const float*)d_in[16], (const float*)d_in[17],
                  (const float*)d_in[18], (const float*)d_in[19],
                  (const float*)d_in[20], (const float*)d_in[21]};
  NetParams P2 = {(const float*)d_in[22], (const float*)d_in[23],
                  (const float*)d_in[24], (const float*)d_in[25],
                  (const float*)d_in[26], (const float*)d_in[27]};
  float* ws = (float*)d_ws;
  float* out = (float*)d_out;
  _Float16* wt = (_Float16*)((char*)d_ws + WT_BYTE_OFF);

  hipLaunchKernelGGL(prep_kernel, dim3((WT_COUNT + 255) / 256), dim3(256), 0, stream,
                     P1.Wh, P2.Wh, wt);
  const int NBLK = NINT_BLK + 2 * NRES_BLK + 2 * NBND_BLK;
  hipLaunchKernelGGL(fused_kernel, dim3(NBLK), dim3(256), 0, stream,
                     xb1, yb1, ub1, xb2, yb2, ub2,
                     xf1, yf1, ff1, xf2, yf2, ff2,
                     xi1, yi1, fi1, P1, P2, wt, ws);
  hipLaunchKernelGGL(combine_a_kernel, dim3(13), dim3(256), 0, stream,
                     ws, ws + WS_SUMS);
  hipLaunchKernelGGL(combine_b_kernel, dim3(1), dim3(64), 0, stream,
                     ws + WS_SUMS, iw, out);
}